// Round 1
// baseline (435.470 us; speedup 1.0000x reference)
//
#include <hip/hip_runtime.h>
#include <hip/hip_bf16.h>
#include <stdint.h>

#define T_TOK 8192
#define D_IN  1024
#define N_EXP 8
#define D_OUT 1024

typedef short s8v __attribute__((ext_vector_type(8)));
typedef float f4v __attribute__((ext_vector_type(4)));
typedef unsigned short ushort_t;

__device__ __forceinline__ ushort_t f2bf(float f) {
    uint32_t u = __float_as_uint(f);
    uint32_t r = (u + 0x7fffu + ((u >> 16) & 1u)) >> 16;
    return (ushort_t)r;
}

__device__ __forceinline__ void async_copy16(const void* g, void* lds) {
    __builtin_amdgcn_global_load_lds(
        (const __attribute__((address_space(1))) unsigned int*)g,
        (__attribute__((address_space(3))) unsigned int*)lds,
        16, 0, 0);
}

// ---------------- fill: zero entries + counters ----------------
__global__ void fill_kernel(int* __restrict__ entries, int* __restrict__ cnt,
                            float* __restrict__ psum) {
    int i = blockIdx.x * 256 + threadIdx.x;
    if (i < N_EXP * T_TOK) entries[i] = 0;
    if (i < N_EXP) { cnt[i] = 0; psum[i] = 0.f; }
}

// ---------------- cast + transpose We -> bf16 [E][DOUT][D] ----------------
__global__ void cast_transpose_we(const float* __restrict__ We,
                                  ushort_t* __restrict__ Webt) {
    __shared__ float tile[64][65];
    int e  = blockIdx.z;
    int k0 = blockIdx.y * 64;   // D index
    int h0 = blockIdx.x * 64;   // DOUT index
    int tid = threadIdx.x;
    const float* src = We + ((size_t)e * D_IN + k0) * D_OUT + h0;
#pragma unroll
    for (int i = 0; i < 16; ++i) {
        int lin = i * 256 + tid;
        int r = lin >> 6, c = lin & 63;       // r: k-local, c: h-local
        tile[r][c] = src[(size_t)r * D_OUT + c];
    }
    __syncthreads();
    ushort_t* dst = Webt + ((size_t)e * D_OUT + h0) * D_IN + k0;
#pragma unroll
    for (int i = 0; i < 16; ++i) {
        int lin = i * 256 + tid;
        int r = lin >> 6, c = lin & 63;       // r: h-local, c: k-local
        dst[(size_t)r * D_IN + c] = f2bf(tile[c][r]);
    }
}

// ---------------- router: logits, softmax, top2, lists; fused x->bf16 -------
__global__ void router_kernel(const float* __restrict__ x,
                              const float* __restrict__ Wr,
                              const float* __restrict__ br,
                              ushort_t* __restrict__ xb,
                              float* __restrict__ wslot,
                              int* __restrict__ entries,
                              int* __restrict__ cnt,
                              float* __restrict__ psum) {
    __shared__ float sps[N_EXP];
    int tid  = threadIdx.x;
    int lane = tid & 63;
    int wv   = tid >> 6;
    if (tid < N_EXP) sps[tid] = 0.f;
    __syncthreads();

    int t0 = blockIdx.x * 16 + wv * 4;
    for (int ti = 0; ti < 4; ++ti) {
        int t = t0 + ti;
        float acc[N_EXP];
#pragma unroll
        for (int e = 0; e < N_EXP; ++e) acc[e] = 0.f;
        const float* xrow = x + (size_t)t * D_IN;
        ushort_t* xbrow = xb + (size_t)t * D_IN;
#pragma unroll
        for (int it = 0; it < 4; ++it) {
            int idx = it * 256 + lane * 4;
            float4 xv = *(const float4*)(xrow + idx);
            ushort4 us;
            us.x = f2bf(xv.x); us.y = f2bf(xv.y);
            us.z = f2bf(xv.z); us.w = f2bf(xv.w);
            *(ushort4*)(xbrow + idx) = us;
            const float* wr = Wr + (size_t)idx * N_EXP;
#pragma unroll
            for (int j = 0; j < 4; ++j) {
                float xj = (j == 0) ? xv.x : (j == 1) ? xv.y : (j == 2) ? xv.z : xv.w;
#pragma unroll
                for (int e = 0; e < N_EXP; ++e)
                    acc[e] += xj * wr[j * N_EXP + e];
            }
        }
        // wave reduction (64 lanes)
#pragma unroll
        for (int e = 0; e < N_EXP; ++e) {
            float v = acc[e];
#pragma unroll
            for (int off = 32; off; off >>= 1) v += __shfl_xor(v, off, 64);
            acc[e] = v + br[e];
        }
        // softmax (fp32, matches ref ordering)
        float m = acc[0];
#pragma unroll
        for (int e = 1; e < N_EXP; ++e) m = fmaxf(m, acc[e]);
        float Z = 0.f;
        float p[N_EXP];
#pragma unroll
        for (int e = 0; e < N_EXP; ++e) { p[e] = expf(acc[e] - m); Z += p[e]; }
        float invZ = 1.f / Z;
#pragma unroll
        for (int e = 0; e < N_EXP; ++e) p[e] *= invZ;
        // top-2, lowest index wins ties (strict >)
        int i0 = 0; float b0 = p[0];
#pragma unroll
        for (int e = 1; e < N_EXP; ++e) if (p[e] > b0) { b0 = p[e]; i0 = e; }
        int i1 = (i0 == 0) ? 1 : 0; float b1 = p[i1];
#pragma unroll
        for (int e = 0; e < N_EXP; ++e)
            if (e != i0 && p[e] > b1) { b1 = p[e]; i1 = e; }
        float denom = b0 + b1 + 1e-9f;
        float w0 = b0 / denom, w1 = b1 / denom;

        if (lane == 0) {
            wslot[2 * t]     = w0;
            wslot[2 * t + 1] = w1;
            int pos0 = atomicAdd(&cnt[i0], 1);
            entries[i0 * T_TOK + pos0] = 2 * t;
            int pos1 = atomicAdd(&cnt[i1], 1);
            entries[i1 * T_TOK + pos1] = 2 * t + 1;
#pragma unroll
            for (int e = 0; e < N_EXP; ++e) atomicAdd(&sps[e], p[e]);
        }
    }
    __syncthreads();
    if (tid < N_EXP) atomicAdd(&psum[tid], sps[tid]);
}

// ---------------- aux loss ----------------
__global__ void aux_kernel(const float* __restrict__ psum,
                           const int* __restrict__ cnt,
                           float* __restrict__ out) {
    if (threadIdx.x == 0 && blockIdx.x == 0) {
        float s = 0.f;
#pragma unroll
        for (int e = 0; e < N_EXP; ++e)
            s += (psum[e] / (float)T_TOK) * ((float)cnt[e] / (float)(T_TOK * 2));
        out[(size_t)T_TOK * D_OUT] = (float)N_EXP * s;
    }
}

// ---------------- grouped GEMM: yslot[entry][h] = w * (x[tok] . We[e][:,h] + be) --
__global__ __launch_bounds__(256)
void moe_gemm(const ushort_t* __restrict__ xb,
              const ushort_t* __restrict__ Webt,
              const float* __restrict__ be,
              const int* __restrict__ entries,
              const int* __restrict__ cnt,
              const float* __restrict__ wslot,
              float* __restrict__ yslot) {
    int e = blockIdx.z;
    int cnte = cnt[e];
    int bm = blockIdx.y;
    if (bm * 128 >= cnte) return;
    int bn = blockIdx.x;

    __shared__ __attribute__((aligned(16))) ushort_t As[128 * 32];
    __shared__ __attribute__((aligned(16))) ushort_t Bs[128 * 32];

    int tid    = threadIdx.x;
    int lane   = tid & 63;
    int wv     = tid >> 6;
    int lane15 = lane & 15;
    int quad   = lane >> 4;
    int wm = (wv >> 1) * 64;
    int wn = (wv & 1) * 64;

    // staging addresses (fixed across K loop)
    int rA    = tid >> 2;      // 0..63
    int chunk = tid & 3;
    const int* epe = entries + e * T_TOK;
    int tok0 = epe[bm * 128 + rA] >> 1;
    int tok1 = epe[bm * 128 + rA + 64] >> 1;
    const ushort_t* gA0 = xb + (size_t)tok0 * D_IN + chunk * 8;
    const ushort_t* gA1 = xb + (size_t)tok1 * D_IN + chunk * 8;
    const ushort_t* WB  = Webt + (size_t)e * D_IN * D_OUT
                               + (size_t)(bn * 128) * D_IN + chunk * 8;
    const ushort_t* gB0 = WB + (size_t)rA * D_IN;
    const ushort_t* gB1 = WB + (size_t)(rA + 64) * D_IN;
    // wave-uniform LDS bases
    char* asBase = (char*)As + wv * 1024;
    char* bsBase = (char*)Bs + wv * 1024;

    f4v acc[4][4];
#pragma unroll
    for (int mi = 0; mi < 4; ++mi)
#pragma unroll
        for (int ni = 0; ni < 4; ++ni)
            acc[mi][ni] = (f4v){0.f, 0.f, 0.f, 0.f};

    for (int k0 = 0; k0 < D_IN; k0 += 32) {
        __syncthreads();
        async_copy16(gA0 + k0, asBase);
        async_copy16(gA1 + k0, asBase + 4096);
        async_copy16(gB0 + k0, bsBase);
        async_copy16(gB1 + k0, bsBase + 4096);
        __syncthreads();

        s8v a[4], b[4];
#pragma unroll
        for (int mi = 0; mi < 4; ++mi)
            a[mi] = *(const s8v*)(As + (wm + mi * 16 + lane15) * 32 + quad * 8);
#pragma unroll
        for (int ni = 0; ni < 4; ++ni)
            b[ni] = *(const s8v*)(Bs + (wn + ni * 16 + lane15) * 32 + quad * 8);
#pragma unroll
        for (int mi = 0; mi < 4; ++mi)
#pragma unroll
            for (int ni = 0; ni < 4; ++ni)
                acc[mi][ni] = __builtin_amdgcn_mfma_f32_16x16x32_bf16(
                    a[mi], b[ni], acc[mi][ni], 0, 0, 0);
    }

    // epilogue: scale by gate weight, add bias, scatter to yslot
    int   ent[4][4];
    float wgt[4][4];
    bool  val[4][4];
#pragma unroll
    for (int mi = 0; mi < 4; ++mi)
#pragma unroll
        for (int r = 0; r < 4; ++r) {
            int grow = bm * 128 + wm + mi * 16 + quad * 4 + r;
            bool v = grow < cnte;
            int en = v ? epe[grow] : 0;
            ent[mi][r] = en;
            wgt[mi][r] = v ? wslot[en] : 0.f;
            val[mi][r] = v;
        }
#pragma unroll
    for (int ni = 0; ni < 4; ++ni) {
        int col = bn * 128 + wn + ni * 16 + lane15;
        float bev = be[e * D_OUT + col];
#pragma unroll
        for (int mi = 0; mi < 4; ++mi)
#pragma unroll
            for (int r = 0; r < 4; ++r)
                if (val[mi][r])
                    yslot[(size_t)ent[mi][r] * D_OUT + col] =
                        wgt[mi][r] * (acc[mi][ni][r] + bev);
    }
}

// ---------------- combine: y[t] = yslot[2t] + yslot[2t+1] ----------------
__global__ void combine_kernel(const float* __restrict__ yslot,
                               float* __restrict__ out) {
    size_t i = ((size_t)blockIdx.x * 256 + threadIdx.x) * 4;
    size_t t = i >> 10;
    size_t h = i & 1023;
    float4 a = *(const float4*)(yslot + (2 * t) * D_OUT + h);
    float4 b = *(const float4*)(yslot + (2 * t + 1) * D_OUT + h);
    float4 o;
    o.x = a.x + b.x; o.y = a.y + b.y; o.z = a.z + b.z; o.w = a.w + b.w;
    *(float4*)(out + i) = o;
}

extern "C" void kernel_launch(void* const* d_in, const int* in_sizes, int n_in,
                              void* d_out, int out_size, void* d_ws, size_t ws_size,
                              hipStream_t stream) {
    const float* x  = (const float*)d_in[0];
    const float* Wr = (const float*)d_in[1];
    const float* br = (const float*)d_in[2];
    const float* We = (const float*)d_in[3];
    const float* be = (const float*)d_in[4];
    float* out = (float*)d_out;

    char* ws = (char*)d_ws;
    ushort_t* xb    = (ushort_t*)(ws);                      // 16 MiB
    ushort_t* Webt  = (ushort_t*)(ws + 16777216);           // 16 MiB
    float*    yslot = (float*)(ws + 33554432);              // 64 MiB
    int*      entries = (int*)(ws + 100663296);             // 256 KiB
    float*    wslot = (float*)(ws + 100925440);             // 64 KiB
    float*    psum  = (float*)(ws + 100990976);             // 32 B
    int*      cnt   = (int*)(ws + 100991232);               // 32 B

    hipLaunchKernelGGL(fill_kernel, dim3(256), dim3(256), 0, stream,
                       entries, cnt, psum);
    hipLaunchKernelGGL(cast_transpose_we, dim3(16, 16, 8), dim3(256), 0, stream,
                       We, Webt);
    hipLaunchKernelGGL(router_kernel, dim3(512), dim3(256), 0, stream,
                       x, Wr, br, xb, wslot, entries, cnt, psum);
    hipLaunchKernelGGL(aux_kernel, dim3(1), dim3(64), 0, stream,
                       psum, cnt, out);
    hipLaunchKernelGGL(moe_gemm, dim3(8, 64, 8), dim3(256), 0, stream,
                       xb, Webt, be, entries, cnt, wslot, yslot);
    hipLaunchKernelGGL(combine_kernel, dim3(8192), dim3(256), 0, stream,
                       yslot, out);
}

// Round 2
// 273.868 us; speedup vs baseline: 1.5901x; 1.5901x over previous
//
#include <hip/hip_runtime.h>
#include <hip/hip_bf16.h>
#include <stdint.h>

#define T_TOK 8192
#define D_IN  1024
#define N_EXP 8
#define D_OUT 1024

typedef short s8v __attribute__((ext_vector_type(8)));
typedef float f4v __attribute__((ext_vector_type(4)));
typedef unsigned short ushort_t;

__device__ __forceinline__ ushort_t f2bf(float f) {
    uint32_t u = __float_as_uint(f);
    uint32_t r = (u + 0x7fffu + ((u >> 16) & 1u)) >> 16;
    return (ushort_t)r;
}

__device__ __forceinline__ void async_copy16(const void* g, void* lds) {
    __builtin_amdgcn_global_load_lds(
        (const __attribute__((address_space(1))) unsigned int*)g,
        (__attribute__((address_space(3))) unsigned int*)lds,
        16, 0, 0);
}

// ---------------- fill: zero entries + counters ----------------
__global__ void fill_kernel(int* __restrict__ entries, int* __restrict__ cnt,
                            float* __restrict__ psum) {
    int i = blockIdx.x * 256 + threadIdx.x;
    if (i < N_EXP * T_TOK) entries[i] = 0;
    if (i < N_EXP) { cnt[i] = 0; psum[i] = 0.f; }
}

// ---------------- streaming cast x -> bf16 ----------------
__global__ void cast_x_kernel(const float* __restrict__ x,
                              ushort_t* __restrict__ xb) {
    size_t i = ((size_t)blockIdx.x * 256 + threadIdx.x) * 4;
    float4 v = *(const float4*)(x + i);
    ushort4 u;
    u.x = f2bf(v.x); u.y = f2bf(v.y); u.z = f2bf(v.z); u.w = f2bf(v.w);
    *(ushort4*)(xb + i) = u;
}

// ---------------- cast + transpose We -> bf16 [E][DOUT][D] ----------------
__global__ void cast_transpose_we(const float* __restrict__ We,
                                  ushort_t* __restrict__ Webt) {
    __shared__ float tile[64][65];
    int e  = blockIdx.z;
    int k0 = blockIdx.y * 64;   // D index
    int h0 = blockIdx.x * 64;   // DOUT index
    int tid = threadIdx.x;
    const float* src = We + ((size_t)e * D_IN + k0) * D_OUT + h0;
#pragma unroll
    for (int it = 0; it < 4; ++it) {
        int lin = it * 256 + tid;         // 0..1023
        int r = lin >> 4;                 // k-local row 0..63
        int c4 = (lin & 15) * 4;          // h-local col
        float4 v = *(const float4*)(src + (size_t)r * D_OUT + c4);
        tile[r][c4]     = v.x; tile[r][c4 + 1] = v.y;
        tile[r][c4 + 2] = v.z; tile[r][c4 + 3] = v.w;
    }
    __syncthreads();
    ushort_t* dst = Webt + ((size_t)e * D_OUT + h0) * D_IN + k0;
#pragma unroll
    for (int it = 0; it < 4; ++it) {
        int lin = it * 256 + tid;
        int h = lin >> 4;                 // h-local row
        int k4 = (lin & 15) * 4;          // k-local col
        ushort4 u;
        u.x = f2bf(tile[k4][h]);     u.y = f2bf(tile[k4 + 1][h]);
        u.z = f2bf(tile[k4 + 2][h]); u.w = f2bf(tile[k4 + 3][h]);
        *(ushort4*)(dst + (size_t)h * D_IN + k4) = u;
    }
}

// ---------------- router: 1 token per lane, D split across 4 waves ----------
__global__ __launch_bounds__(256)
void router_kernel(const float* __restrict__ x,
                   const float* __restrict__ Wr,
                   const float* __restrict__ br,
                   float* __restrict__ wslot,
                   int* __restrict__ entries,
                   int* __restrict__ cnt,
                   float* __restrict__ psum) {
    __shared__ float red[4][64][N_EXP];   // [wave][token-lane][expert]
    __shared__ int lcnt[N_EXP];
    __shared__ int gbase[N_EXP];

    int tid  = threadIdx.x;
    int lane = tid & 63;
    int wv   = tid >> 6;
    int t    = blockIdx.x * 64 + lane;

    if (wv == 1 && lane < N_EXP) lcnt[lane] = 0;

    const float* xrow = x + (size_t)t * D_IN + wv * 256;
    const float* wrp  = Wr + wv * 256 * N_EXP;   // wave-uniform base

    float acc[N_EXP];
#pragma unroll
    for (int e = 0; e < N_EXP; ++e) acc[e] = 0.f;

#pragma unroll 8
    for (int i = 0; i < 256; i += 4) {
        float4 xv = *(const float4*)(xrow + i);
        const float* wr = wrp + i * N_EXP;      // wave-uniform -> s_load
#pragma unroll
        for (int j = 0; j < 4; ++j) {
            float xj = (j == 0) ? xv.x : (j == 1) ? xv.y : (j == 2) ? xv.z : xv.w;
#pragma unroll
            for (int e = 0; e < N_EXP; ++e)
                acc[e] += xj * wr[j * N_EXP + e];
        }
    }
#pragma unroll
    for (int e = 0; e < N_EXP; ++e) red[wv][lane][e] = acc[e];
    __syncthreads();

    int i0 = 0, i1 = 1, lpos0 = 0, lpos1 = 0;
    if (wv == 0) {
        float p[N_EXP];
#pragma unroll
        for (int e = 0; e < N_EXP; ++e)
            p[e] = red[0][lane][e] + red[1][lane][e]
                 + red[2][lane][e] + red[3][lane][e] + br[e];
        // softmax (fp32)
        float m = p[0];
#pragma unroll
        for (int e = 1; e < N_EXP; ++e) m = fmaxf(m, p[e]);
        float Z = 0.f;
#pragma unroll
        for (int e = 0; e < N_EXP; ++e) { p[e] = expf(p[e] - m); Z += p[e]; }
        float invZ = 1.f / Z;
#pragma unroll
        for (int e = 0; e < N_EXP; ++e) p[e] *= invZ;
        // top-2, lowest index wins ties (strict >)
        float b0 = p[0];
#pragma unroll
        for (int e = 1; e < N_EXP; ++e) if (p[e] > b0) { b0 = p[e]; i0 = e; }
        i1 = (i0 == 0) ? 1 : 0; float b1 = p[i1];
#pragma unroll
        for (int e = 0; e < N_EXP; ++e)
            if (e != i0 && p[e] > b1) { b1 = p[e]; i1 = e; }
        float denom = b0 + b1 + 1e-9f;
        float2 w01; w01.x = b0 / denom; w01.y = b1 / denom;
        *(float2*)(wslot + 2 * t) = w01;
        // aux-loss partial: sum p over tokens (wave reduce, 1 atomic/expert)
#pragma unroll
        for (int e = 0; e < N_EXP; ++e) {
            float v = p[e];
#pragma unroll
            for (int off = 32; off; off >>= 1) v += __shfl_xor(v, off, 64);
            if (lane == 0) atomicAdd(&psum[e], v);
        }
        // local histogram slots
        lpos0 = atomicAdd(&lcnt[i0], 1);
        lpos1 = atomicAdd(&lcnt[i1], 1);
    }
    __syncthreads();
    if (tid < N_EXP) gbase[tid] = atomicAdd(&cnt[tid], lcnt[tid]);
    __syncthreads();
    if (wv == 0) {
        entries[i0 * T_TOK + gbase[i0] + lpos0] = 2 * t;
        entries[i1 * T_TOK + gbase[i1] + lpos1] = 2 * t + 1;
    }
}

// ---------------- aux loss ----------------
__global__ void aux_kernel(const float* __restrict__ psum,
                           const int* __restrict__ cnt,
                           float* __restrict__ out) {
    if (threadIdx.x == 0 && blockIdx.x == 0) {
        float s = 0.f;
#pragma unroll
        for (int e = 0; e < N_EXP; ++e)
            s += (psum[e] / (float)T_TOK) * ((float)cnt[e] / (float)(T_TOK * 2));
        out[(size_t)T_TOK * D_OUT] = (float)N_EXP * s;
    }
}

// ---------------- grouped GEMM: yslot[entry][h] = w * (x[tok] . We[e][:,h] + be) --
__global__ __launch_bounds__(256)
void moe_gemm(const ushort_t* __restrict__ xb,
              const ushort_t* __restrict__ Webt,
              const float* __restrict__ be,
              const int* __restrict__ entries,
              const int* __restrict__ cnt,
              const float* __restrict__ wslot,
              float* __restrict__ yslot) {
    int e = blockIdx.z;
    int cnte = cnt[e];
    int bm = blockIdx.y;
    if (bm * 128 >= cnte) return;
    int bn = blockIdx.x;

    __shared__ __attribute__((aligned(16))) ushort_t As[128 * 32];
    __shared__ __attribute__((aligned(16))) ushort_t Bs[128 * 32];

    int tid    = threadIdx.x;
    int lane   = tid & 63;
    int wv     = tid >> 6;
    int lane15 = lane & 15;
    int quad   = lane >> 4;
    int wm = (wv >> 1) * 64;
    int wn = (wv & 1) * 64;

    int rA    = tid >> 2;      // 0..63
    int chunk = tid & 3;
    const int* epe = entries + e * T_TOK;
    int tok0 = epe[bm * 128 + rA] >> 1;
    int tok1 = epe[bm * 128 + rA + 64] >> 1;
    const ushort_t* gA0 = xb + (size_t)tok0 * D_IN + chunk * 8;
    const ushort_t* gA1 = xb + (size_t)tok1 * D_IN + chunk * 8;
    const ushort_t* WB  = Webt + (size_t)e * D_IN * D_OUT
                               + (size_t)(bn * 128) * D_IN + chunk * 8;
    const ushort_t* gB0 = WB + (size_t)rA * D_IN;
    const ushort_t* gB1 = WB + (size_t)(rA + 64) * D_IN;
    char* asBase = (char*)As + wv * 1024;
    char* bsBase = (char*)Bs + wv * 1024;

    f4v acc[4][4];
#pragma unroll
    for (int mi = 0; mi < 4; ++mi)
#pragma unroll
        for (int ni = 0; ni < 4; ++ni)
            acc[mi][ni] = (f4v){0.f, 0.f, 0.f, 0.f};

    for (int k0 = 0; k0 < D_IN; k0 += 32) {
        __syncthreads();
        async_copy16(gA0 + k0, asBase);
        async_copy16(gA1 + k0, asBase + 4096);
        async_copy16(gB0 + k0, bsBase);
        async_copy16(gB1 + k0, bsBase + 4096);
        __syncthreads();

        s8v a[4], b[4];
#pragma unroll
        for (int mi = 0; mi < 4; ++mi)
            a[mi] = *(const s8v*)(As + (wm + mi * 16 + lane15) * 32 + quad * 8);
#pragma unroll
        for (int ni = 0; ni < 4; ++ni)
            b[ni] = *(const s8v*)(Bs + (wn + ni * 16 + lane15) * 32 + quad * 8);
#pragma unroll
        for (int mi = 0; mi < 4; ++mi)
#pragma unroll
            for (int ni = 0; ni < 4; ++ni)
                acc[mi][ni] = __builtin_amdgcn_mfma_f32_16x16x32_bf16(
                    a[mi], b[ni], acc[mi][ni], 0, 0, 0);
    }

    int   ent[4][4];
    float wgt[4][4];
    bool  val[4][4];
#pragma unroll
    for (int mi = 0; mi < 4; ++mi)
#pragma unroll
        for (int r = 0; r < 4; ++r) {
            int grow = bm * 128 + wm + mi * 16 + quad * 4 + r;
            bool v = grow < cnte;
            int en = v ? epe[grow] : 0;
            ent[mi][r] = en;
            wgt[mi][r] = v ? wslot[en] : 0.f;
            val[mi][r] = v;
        }
#pragma unroll
    for (int ni = 0; ni < 4; ++ni) {
        int col = bn * 128 + wn + ni * 16 + lane15;
        float bev = be[e * D_OUT + col];
#pragma unroll
        for (int mi = 0; mi < 4; ++mi)
#pragma unroll
            for (int r = 0; r < 4; ++r)
                if (val[mi][r])
                    yslot[(size_t)ent[mi][r] * D_OUT + col] =
                        wgt[mi][r] * (acc[mi][ni][r] + bev);
    }
}

// ---------------- combine: y[t] = yslot[2t] + yslot[2t+1] ----------------
__global__ void combine_kernel(const float* __restrict__ yslot,
                               float* __restrict__ out) {
    size_t i = ((size_t)blockIdx.x * 256 + threadIdx.x) * 4;
    size_t t = i >> 10;
    size_t h = i & 1023;
    float4 a = *(const float4*)(yslot + (2 * t) * D_OUT + h);
    float4 b = *(const float4*)(yslot + (2 * t + 1) * D_OUT + h);
    float4 o;
    o.x = a.x + b.x; o.y = a.y + b.y; o.z = a.z + b.z; o.w = a.w + b.w;
    *(float4*)(out + i) = o;
}

extern "C" void kernel_launch(void* const* d_in, const int* in_sizes, int n_in,
                              void* d_out, int out_size, void* d_ws, size_t ws_size,
                              hipStream_t stream) {
    const float* x  = (const float*)d_in[0];
    const float* Wr = (const float*)d_in[1];
    const float* br = (const float*)d_in[2];
    const float* We = (const float*)d_in[3];
    const float* be = (const float*)d_in[4];
    float* out = (float*)d_out;

    char* ws = (char*)d_ws;
    ushort_t* xb    = (ushort_t*)(ws);                      // 16 MiB
    ushort_t* Webt  = (ushort_t*)(ws + 16777216);           // 16 MiB
    float*    yslot = (float*)(ws + 33554432);              // 64 MiB
    int*      entries = (int*)(ws + 100663296);             // 256 KiB
    float*    wslot = (float*)(ws + 100925440);             // 64 KiB
    float*    psum  = (float*)(ws + 100990976);             // 32 B
    int*      cnt   = (int*)(ws + 100991232);               // 32 B

    hipLaunchKernelGGL(fill_kernel, dim3(256), dim3(256), 0, stream,
                       entries, cnt, psum);
    hipLaunchKernelGGL(cast_x_kernel, dim3(8192), dim3(256), 0, stream,
                       x, xb);
    hipLaunchKernelGGL(cast_transpose_we, dim3(16, 16, 8), dim3(256), 0, stream,
                       We, Webt);
    hipLaunchKernelGGL(router_kernel, dim3(128), dim3(256), 0, stream,
                       x, Wr, br, wslot, entries, cnt, psum);
    hipLaunchKernelGGL(aux_kernel, dim3(1), dim3(64), 0, stream,
                       psum, cnt, out);
    hipLaunchKernelGGL(moe_gemm, dim3(8, 64, 8), dim3(256), 0, stream,
                       xb, Webt, be, entries, cnt, wslot, yslot);
    hipLaunchKernelGGL(combine_kernel, dim3(8192), dim3(256), 0, stream,
                       yslot, out);
}

// Round 3
// 249.723 us; speedup vs baseline: 1.7438x; 1.0967x over previous
//
#include <hip/hip_runtime.h>
#include <hip/hip_bf16.h>
#include <stdint.h>

#define T_TOK 8192
#define D_IN  1024
#define N_EXP 8
#define D_OUT 1024

#define BM 128
#define BN 64
#define BK 32

typedef short s8v __attribute__((ext_vector_type(8)));
typedef float f4v __attribute__((ext_vector_type(4)));
typedef unsigned short ushort_t;

__device__ __forceinline__ ushort_t f2bf(float f) {
    uint32_t u = __float_as_uint(f);
    uint32_t r = (u + 0x7fffu + ((u >> 16) & 1u)) >> 16;
    return (ushort_t)r;
}

__device__ __forceinline__ float bf2f(ushort_t u) {
    return __uint_as_float(((uint32_t)u) << 16);
}

__device__ __forceinline__ void async_copy16(const void* g, void* lds) {
    __builtin_amdgcn_global_load_lds(
        (const __attribute__((address_space(1))) unsigned int*)g,
        (__attribute__((address_space(3))) unsigned int*)lds,
        16, 0, 0);
}

// ---------------- fill: zero entries + counters ----------------
__global__ void fill_kernel(int* __restrict__ entries, int* __restrict__ cnt,
                            float* __restrict__ psum) {
    int i = blockIdx.x * 256 + threadIdx.x;
    if (i < N_EXP * T_TOK) entries[i] = 0;
    if (i < N_EXP) { cnt[i] = 0; psum[i] = 0.f; }
}

// ---------------- streaming cast x -> bf16 ----------------
__global__ void cast_x_kernel(const float* __restrict__ x,
                              ushort_t* __restrict__ xb) {
    size_t i = ((size_t)blockIdx.x * 256 + threadIdx.x) * 4;
    float4 v = *(const float4*)(x + i);
    ushort4 u;
    u.x = f2bf(v.x); u.y = f2bf(v.y); u.z = f2bf(v.z); u.w = f2bf(v.w);
    *(ushort4*)(xb + i) = u;
}

// ---------------- cast + transpose We -> bf16 [E][DOUT][D] ----------------
__global__ void cast_transpose_we(const float* __restrict__ We,
                                  ushort_t* __restrict__ Webt) {
    __shared__ float tile[64][65];
    int e  = blockIdx.z;
    int k0 = blockIdx.y * 64;   // D index
    int h0 = blockIdx.x * 64;   // DOUT index
    int tid = threadIdx.x;
    const float* src = We + ((size_t)e * D_IN + k0) * D_OUT + h0;
#pragma unroll
    for (int it = 0; it < 4; ++it) {
        int lin = it * 256 + tid;
        int r = lin >> 4;
        int c4 = (lin & 15) * 4;
        float4 v = *(const float4*)(src + (size_t)r * D_OUT + c4);
        tile[r][c4]     = v.x; tile[r][c4 + 1] = v.y;
        tile[r][c4 + 2] = v.z; tile[r][c4 + 3] = v.w;
    }
    __syncthreads();
    ushort_t* dst = Webt + ((size_t)e * D_OUT + h0) * D_IN + k0;
#pragma unroll
    for (int it = 0; it < 4; ++it) {
        int lin = it * 256 + tid;
        int h = lin >> 4;
        int k4 = (lin & 15) * 4;
        ushort4 u;
        u.x = f2bf(tile[k4][h]);     u.y = f2bf(tile[k4 + 1][h]);
        u.z = f2bf(tile[k4 + 2][h]); u.w = f2bf(tile[k4 + 3][h]);
        *(ushort4*)(dst + (size_t)h * D_IN + k4) = u;
    }
}

// ---------------- router: 1 token per lane, D split across 4 waves ----------
__global__ __launch_bounds__(256)
void router_kernel(const float* __restrict__ x,
                   const float* __restrict__ Wr,
                   const float* __restrict__ br,
                   float* __restrict__ wslot,
                   int* __restrict__ entries,
                   int* __restrict__ cnt,
                   float* __restrict__ psum) {
    __shared__ float red[4][64][N_EXP];
    __shared__ int lcnt[N_EXP];
    __shared__ int gbase[N_EXP];

    int tid  = threadIdx.x;
    int lane = tid & 63;
    int wv   = tid >> 6;
    int t    = blockIdx.x * 64 + lane;

    if (wv == 1 && lane < N_EXP) lcnt[lane] = 0;

    const float* xrow = x + (size_t)t * D_IN + wv * 256;
    const float* wrp  = Wr + wv * 256 * N_EXP;

    float acc[N_EXP];
#pragma unroll
    for (int e = 0; e < N_EXP; ++e) acc[e] = 0.f;

#pragma unroll 8
    for (int i = 0; i < 256; i += 4) {
        float4 xv = *(const float4*)(xrow + i);
        const float* wr = wrp + i * N_EXP;
#pragma unroll
        for (int j = 0; j < 4; ++j) {
            float xj = (j == 0) ? xv.x : (j == 1) ? xv.y : (j == 2) ? xv.z : xv.w;
#pragma unroll
            for (int e = 0; e < N_EXP; ++e)
                acc[e] += xj * wr[j * N_EXP + e];
        }
    }
#pragma unroll
    for (int e = 0; e < N_EXP; ++e) red[wv][lane][e] = acc[e];
    __syncthreads();

    int i0 = 0, i1 = 1, lpos0 = 0, lpos1 = 0;
    if (wv == 0) {
        float p[N_EXP];
#pragma unroll
        for (int e = 0; e < N_EXP; ++e)
            p[e] = red[0][lane][e] + red[1][lane][e]
                 + red[2][lane][e] + red[3][lane][e] + br[e];
        float m = p[0];
#pragma unroll
        for (int e = 1; e < N_EXP; ++e) m = fmaxf(m, p[e]);
        float Z = 0.f;
#pragma unroll
        for (int e = 0; e < N_EXP; ++e) { p[e] = expf(p[e] - m); Z += p[e]; }
        float invZ = 1.f / Z;
#pragma unroll
        for (int e = 0; e < N_EXP; ++e) p[e] *= invZ;
        float b0 = p[0];
#pragma unroll
        for (int e = 1; e < N_EXP; ++e) if (p[e] > b0) { b0 = p[e]; i0 = e; }
        i1 = (i0 == 0) ? 1 : 0; float b1 = p[i1];
#pragma unroll
        for (int e = 0; e < N_EXP; ++e)
            if (e != i0 && p[e] > b1) { b1 = p[e]; i1 = e; }
        float denom = b0 + b1 + 1e-9f;
        float2 w01; w01.x = b0 / denom; w01.y = b1 / denom;
        *(float2*)(wslot + 2 * t) = w01;
#pragma unroll
        for (int e = 0; e < N_EXP; ++e) {
            float v = p[e];
#pragma unroll
            for (int off = 32; off; off >>= 1) v += __shfl_xor(v, off, 64);
            if (lane == 0) atomicAdd(&psum[e], v);
        }
        lpos0 = atomicAdd(&lcnt[i0], 1);
        lpos1 = atomicAdd(&lcnt[i1], 1);
    }
    __syncthreads();
    if (tid < N_EXP) gbase[tid] = atomicAdd(&cnt[tid], lcnt[tid]);
    __syncthreads();
    if (wv == 0) {
        entries[i0 * T_TOK + gbase[i0] + lpos0] = 2 * t;
        entries[i1 * T_TOK + gbase[i1] + lpos1] = 2 * t + 1;
    }
}

// ---------------- grouped GEMM, 128x64 tile, dbuf LDS, bf16 yslot ----------
__global__ __launch_bounds__(256, 4)
void moe_gemm(const ushort_t* __restrict__ xb,
              const ushort_t* __restrict__ Webt,
              const float* __restrict__ be,
              const int* __restrict__ entries,
              const int* __restrict__ cnt,
              const float* __restrict__ wslot,
              ushort_t* __restrict__ yslot) {
    int e = blockIdx.z;
    int cnte = cnt[e];
    int bm = blockIdx.y;
    if (bm * BM >= cnte) return;
    int bn = blockIdx.x;

    __shared__ __attribute__((aligned(16))) ushort_t As[2][BM * BK];
    __shared__ __attribute__((aligned(16))) ushort_t Bs[2][BN * BK];

    int tid    = threadIdx.x;
    int lane   = tid & 63;
    int wv     = tid >> 6;
    int lane15 = lane & 15;
    int quad   = lane >> 4;
    int wm = (wv >> 1) * 64;   // 0 or 64
    int wn = (wv & 1) * 32;    // 0 or 32

    int rA    = tid >> 2;      // 0..63
    int chunk = tid & 3;
    const int* epe = entries + e * T_TOK;
    int tok0 = epe[bm * BM + rA] >> 1;
    int tok1 = epe[bm * BM + 64 + rA] >> 1;
    const ushort_t* gA0 = xb + (size_t)tok0 * D_IN + chunk * 8;
    const ushort_t* gA1 = xb + (size_t)tok1 * D_IN + chunk * 8;
    const ushort_t* gB0 = Webt + (size_t)e * D_IN * D_OUT
                        + (size_t)(bn * BN + rA) * D_IN + chunk * 8;
    int ldsOff = wv * 1024;    // wave-uniform byte offset

    f4v acc[4][2];
#pragma unroll
    for (int mi = 0; mi < 4; ++mi)
#pragma unroll
        for (int ni = 0; ni < 2; ++ni)
            acc[mi][ni] = (f4v){0.f, 0.f, 0.f, 0.f};

    // prologue: stage k0 = 0 into buffer 0
    async_copy16(gA0, (char*)As[0] + ldsOff);
    async_copy16(gA1, (char*)As[0] + 4096 + ldsOff);
    async_copy16(gB0, (char*)Bs[0] + ldsOff);

    for (int k0 = 0; k0 < D_IN; k0 += BK) {
        int cur = (k0 >> 5) & 1;
        __syncthreads();                    // drains loads into buf[cur]
        if (k0 + BK < D_IN) {
            int nxt = cur ^ 1;
            async_copy16(gA0 + k0 + BK, (char*)As[nxt] + ldsOff);
            async_copy16(gA1 + k0 + BK, (char*)As[nxt] + 4096 + ldsOff);
            async_copy16(gB0 + k0 + BK, (char*)Bs[nxt] + ldsOff);
        }
        s8v a[4], b[2];
#pragma unroll
        for (int mi = 0; mi < 4; ++mi)
            a[mi] = *(const s8v*)(&As[cur][0] + (wm + mi * 16 + lane15) * BK + quad * 8);
#pragma unroll
        for (int ni = 0; ni < 2; ++ni)
            b[ni] = *(const s8v*)(&Bs[cur][0] + (wn + ni * 16 + lane15) * BK + quad * 8);
#pragma unroll
        for (int mi = 0; mi < 4; ++mi)
#pragma unroll
            for (int ni = 0; ni < 2; ++ni)
                acc[mi][ni] = __builtin_amdgcn_mfma_f32_16x16x32_bf16(
                    a[mi], b[ni], acc[mi][ni], 0, 0, 0);
    }

    // epilogue: scale by gate weight, add bias, store bf16 to yslot
    int   ent[4][4];
    float wgt[4][4];
    bool  val[4][4];
#pragma unroll
    for (int mi = 0; mi < 4; ++mi)
#pragma unroll
        for (int r = 0; r < 4; ++r) {
            int grow = bm * BM + wm + mi * 16 + quad * 4 + r;
            bool v = grow < cnte;
            int en = v ? epe[grow] : 0;
            ent[mi][r] = en;
            wgt[mi][r] = v ? wslot[en] : 0.f;
            val[mi][r] = v;
        }
#pragma unroll
    for (int ni = 0; ni < 2; ++ni) {
        int col = bn * BN + wn + ni * 16 + lane15;
        float bev = be[e * D_OUT + col];
#pragma unroll
        for (int mi = 0; mi < 4; ++mi)
#pragma unroll
            for (int r = 0; r < 4; ++r)
                if (val[mi][r])
                    yslot[(size_t)ent[mi][r] * D_OUT + col] =
                        f2bf(wgt[mi][r] * (acc[mi][ni][r] + bev));
    }
}

// ---------------- combine (+ fused aux): y[t] = ys[2t] + ys[2t+1] -----------
__global__ void combine_kernel(const ushort_t* __restrict__ yslot,
                               const float* __restrict__ psum,
                               const int* __restrict__ cnt,
                               float* __restrict__ out) {
    size_t i = ((size_t)blockIdx.x * 256 + threadIdx.x) * 4;
    size_t t = i >> 10;
    size_t h = i & 1023;
    const ushort_t* p0 = yslot + (2 * t) * D_OUT + h;
    ushort4 a = *(const ushort4*)p0;
    ushort4 b = *(const ushort4*)(p0 + D_OUT);
    float4 o;
    o.x = bf2f(a.x) + bf2f(b.x);
    o.y = bf2f(a.y) + bf2f(b.y);
    o.z = bf2f(a.z) + bf2f(b.z);
    o.w = bf2f(a.w) + bf2f(b.w);
    *(float4*)(out + i) = o;
    if (i == 0) {
        float s = 0.f;
#pragma unroll
        for (int e = 0; e < N_EXP; ++e)
            s += (psum[e] / (float)T_TOK) * ((float)cnt[e] / (float)(T_TOK * 2));
        out[(size_t)T_TOK * D_OUT] = (float)N_EXP * s;
    }
}

extern "C" void kernel_launch(void* const* d_in, const int* in_sizes, int n_in,
                              void* d_out, int out_size, void* d_ws, size_t ws_size,
                              hipStream_t stream) {
    const float* x  = (const float*)d_in[0];
    const float* Wr = (const float*)d_in[1];
    const float* br = (const float*)d_in[2];
    const float* We = (const float*)d_in[3];
    const float* be = (const float*)d_in[4];
    float* out = (float*)d_out;

    char* ws = (char*)d_ws;
    ushort_t* xb      = (ushort_t*)(ws);                    // 16 MiB
    ushort_t* Webt    = (ushort_t*)(ws + 16777216);         // 16 MiB
    ushort_t* yslot   = (ushort_t*)(ws + 33554432);         // 32 MiB (bf16)
    int*      entries = (int*)(ws + 67108864);              // 256 KiB
    float*    wslot   = (float*)(ws + 67371008);            // 64 KiB
    float*    psum    = (float*)(ws + 67436544);            // 32 B
    int*      cnt     = (int*)(ws + 67436576);              // 32 B

    hipLaunchKernelGGL(fill_kernel, dim3(256), dim3(256), 0, stream,
                       entries, cnt, psum);
    hipLaunchKernelGGL(cast_x_kernel, dim3(8192), dim3(256), 0, stream,
                       x, xb);
    hipLaunchKernelGGL(cast_transpose_we, dim3(16, 16, 8), dim3(256), 0, stream,
                       We, Webt);
    hipLaunchKernelGGL(router_kernel, dim3(128), dim3(256), 0, stream,
                       x, Wr, br, wslot, entries, cnt, psum);
    hipLaunchKernelGGL(moe_gemm, dim3(16, 64, 8), dim3(256), 0, stream,
                       xb, Webt, be, entries, cnt, wslot, yslot);
    hipLaunchKernelGGL(combine_kernel, dim3(8192), dim3(256), 0, stream,
                       yslot, psum, cnt, out);
}

// Round 4
// 245.326 us; speedup vs baseline: 1.7751x; 1.0179x over previous
//
#include <hip/hip_runtime.h>
#include <hip/hip_bf16.h>
#include <stdint.h>

#define T_TOK 8192
#define D_IN  1024
#define N_EXP 8
#define D_OUT 1024

#define BM 128
#define BN 128
#define BK 32

typedef short s8v __attribute__((ext_vector_type(8)));
typedef float f4v __attribute__((ext_vector_type(4)));
typedef unsigned short ushort_t;

__device__ __forceinline__ ushort_t f2bf(float f) {
    uint32_t u = __float_as_uint(f);
    uint32_t r = (u + 0x7fffu + ((u >> 16) & 1u)) >> 16;
    return (ushort_t)r;
}

__device__ __forceinline__ float bf2f(ushort_t u) {
    return __uint_as_float(((uint32_t)u) << 16);
}

__device__ __forceinline__ void async_copy16(const void* g, void* lds) {
    __builtin_amdgcn_global_load_lds(
        (const __attribute__((address_space(1))) unsigned int*)g,
        (__attribute__((address_space(3))) unsigned int*)lds,
        16, 0, 0);
}

// ------- cast + transpose We -> bf16 [E][DOUT][D]; block0 zeroes counters ---
__global__ void cast_transpose_we(const float* __restrict__ We,
                                  ushort_t* __restrict__ Webt,
                                  int* __restrict__ cnt,
                                  float* __restrict__ psum) {
    if (blockIdx.x == 0 && blockIdx.y == 0 && blockIdx.z == 0 &&
        threadIdx.x < N_EXP) {
        cnt[threadIdx.x] = 0;
        psum[threadIdx.x] = 0.f;
    }
    __shared__ float tile[64][65];
    int e  = blockIdx.z;
    int k0 = blockIdx.y * 64;   // D index
    int h0 = blockIdx.x * 64;   // DOUT index
    int tid = threadIdx.x;
    const float* src = We + ((size_t)e * D_IN + k0) * D_OUT + h0;
#pragma unroll
    for (int it = 0; it < 4; ++it) {
        int lin = it * 256 + tid;
        int r = lin >> 4;
        int c4 = (lin & 15) * 4;
        float4 v = *(const float4*)(src + (size_t)r * D_OUT + c4);
        tile[r][c4]     = v.x; tile[r][c4 + 1] = v.y;
        tile[r][c4 + 2] = v.z; tile[r][c4 + 3] = v.w;
    }
    __syncthreads();
    ushort_t* dst = Webt + ((size_t)e * D_OUT + h0) * D_IN + k0;
#pragma unroll
    for (int it = 0; it < 4; ++it) {
        int lin = it * 256 + tid;
        int h = lin >> 4;
        int k4 = (lin & 15) * 4;
        ushort4 u;
        u.x = f2bf(tile[k4][h]);     u.y = f2bf(tile[k4 + 1][h]);
        u.z = f2bf(tile[k4 + 2][h]); u.w = f2bf(tile[k4 + 3][h]);
        *(ushort4*)(dst + (size_t)h * D_IN + k4) = u;
    }
}

// ------- router: 1 token/lane, D split across 4 waves; fused x->bf16 cast ---
__global__ __launch_bounds__(256)
void router_kernel(const float* __restrict__ x,
                   const float* __restrict__ Wr,
                   const float* __restrict__ br,
                   ushort_t* __restrict__ xb,
                   float* __restrict__ wslot,
                   int* __restrict__ entries,
                   int* __restrict__ cnt,
                   float* __restrict__ psum) {
    __shared__ float red[4][64][N_EXP];
    __shared__ int lcnt[N_EXP];
    __shared__ int gbase[N_EXP];

    int tid  = threadIdx.x;
    int lane = tid & 63;
    int wv   = tid >> 6;
    int t    = blockIdx.x * 64 + lane;

    if (wv == 1 && lane < N_EXP) lcnt[lane] = 0;

    const float* xrow = x + (size_t)t * D_IN + wv * 256;
    ushort_t* xbrow   = xb + (size_t)t * D_IN + wv * 256;
    const float* wrp  = Wr + wv * 256 * N_EXP;

    float acc[N_EXP];
#pragma unroll
    for (int e = 0; e < N_EXP; ++e) acc[e] = 0.f;

#pragma unroll 8
    for (int i = 0; i < 256; i += 4) {
        float4 xv = *(const float4*)(xrow + i);
        ushort4 u;
        u.x = f2bf(xv.x); u.y = f2bf(xv.y);
        u.z = f2bf(xv.z); u.w = f2bf(xv.w);
        *(ushort4*)(xbrow + i) = u;
        const float* wr = wrp + i * N_EXP;
#pragma unroll
        for (int j = 0; j < 4; ++j) {
            float xj = (j == 0) ? xv.x : (j == 1) ? xv.y : (j == 2) ? xv.z : xv.w;
#pragma unroll
            for (int e = 0; e < N_EXP; ++e)
                acc[e] += xj * wr[j * N_EXP + e];
        }
    }
#pragma unroll
    for (int e = 0; e < N_EXP; ++e) red[wv][lane][e] = acc[e];
    __syncthreads();

    int i0 = 0, i1 = 1, lpos0 = 0, lpos1 = 0;
    if (wv == 0) {
        float p[N_EXP];
#pragma unroll
        for (int e = 0; e < N_EXP; ++e)
            p[e] = red[0][lane][e] + red[1][lane][e]
                 + red[2][lane][e] + red[3][lane][e] + br[e];
        float m = p[0];
#pragma unroll
        for (int e = 1; e < N_EXP; ++e) m = fmaxf(m, p[e]);
        float Z = 0.f;
#pragma unroll
        for (int e = 0; e < N_EXP; ++e) { p[e] = expf(p[e] - m); Z += p[e]; }
        float invZ = 1.f / Z;
#pragma unroll
        for (int e = 0; e < N_EXP; ++e) p[e] *= invZ;
        float b0 = p[0];
#pragma unroll
        for (int e = 1; e < N_EXP; ++e) if (p[e] > b0) { b0 = p[e]; i0 = e; }
        i1 = (i0 == 0) ? 1 : 0; float b1 = p[i1];
#pragma unroll
        for (int e = 0; e < N_EXP; ++e)
            if (e != i0 && p[e] > b1) { b1 = p[e]; i1 = e; }
        float denom = b0 + b1 + 1e-9f;
        float2 w01; w01.x = b0 / denom; w01.y = b1 / denom;
        *(float2*)(wslot + 2 * t) = w01;
#pragma unroll
        for (int e = 0; e < N_EXP; ++e) {
            float v = p[e];
#pragma unroll
            for (int off = 32; off; off >>= 1) v += __shfl_xor(v, off, 64);
            if (lane == 0) atomicAdd(&psum[e], v);
        }
        lpos0 = atomicAdd(&lcnt[i0], 1);
        lpos1 = atomicAdd(&lcnt[i1], 1);
    }
    __syncthreads();
    if (tid < N_EXP) gbase[tid] = atomicAdd(&cnt[tid], lcnt[tid]);
    __syncthreads();
    if (wv == 0) {
        entries[i0 * T_TOK + gbase[i0] + lpos0] = 2 * t;
        entries[i1 * T_TOK + gbase[i1] + lpos1] = 2 * t + 1;
    }
}

// ------- grouped GEMM, 128x128 tile, dbuf LDS, XOR-swizzled chunks,
//         XCD-affinity (expert = blockIdx & 7), bf16 yslot -------------------
__global__ __launch_bounds__(256, 3)
void moe_gemm(const ushort_t* __restrict__ xb,
              const ushort_t* __restrict__ Webt,
              const float* __restrict__ be,
              const int* __restrict__ entries,
              const int* __restrict__ cnt,
              const float* __restrict__ wslot,
              ushort_t* __restrict__ yslot) {
    int idx  = blockIdx.x;
    int e    = idx & 7;          // XCD-affinity: round-robin block->XCD
    int rest = idx >> 3;
    int bn   = rest & 7;         // 0..7  (128-wide N tiles)
    int bm   = rest >> 3;        // 0..63
    int cnte = cnt[e];
    if (bm * BM >= cnte) return;

    __shared__ __attribute__((aligned(16))) ushort_t As[2][BM * BK];
    __shared__ __attribute__((aligned(16))) ushort_t Bs[2][BN * BK];

    int tid    = threadIdx.x;
    int lane   = tid & 63;
    int wv     = tid >> 6;
    int lane15 = lane & 15;
    int quad   = lane >> 4;
    int wm = (wv >> 1) * 64;     // 0 or 64
    int wn = (wv & 1) * 64;      // 0 or 64

    // ---- staging addresses (chunk XOR-swizzle to kill LDS read conflicts) --
    int rA   = tid >> 2;                           // 0..63
    int cper = (tid & 3) ^ ((rA >> 1) & 3);        // permuted 16B chunk
    const int* epe = entries + e * T_TOK;
    int r0 = bm * BM + rA;
    int r1 = r0 + 64;
    int c0 = r0 < cnte ? r0 : cnte - 1;            // clamp (entries not zeroed)
    int c1 = r1 < cnte ? r1 : cnte - 1;
    int tok0 = epe[c0] >> 1;
    int tok1 = epe[c1] >> 1;
    const ushort_t* gA0 = xb + (size_t)tok0 * D_IN + cper * 8;
    const ushort_t* gA1 = xb + (size_t)tok1 * D_IN + cper * 8;
    const ushort_t* WB  = Webt + (size_t)e * D_IN * D_OUT + cper * 8;
    const ushort_t* gB0 = WB + (size_t)(bn * BN + rA) * D_IN;
    const ushort_t* gB1 = WB + (size_t)(bn * BN + rA + 64) * D_IN;
    int ldsOff = wv * 1024;                        // wave-uniform byte offset

    // ---- fragment read offsets (mirror the XOR swizzle) --------------------
    int aoff[4], boff[4];
#pragma unroll
    for (int mi = 0; mi < 4; ++mi) {
        int m = wm + mi * 16 + lane15;
        aoff[mi] = m * 64 + (quad ^ ((m >> 1) & 3)) * 16;
        int n = wn + mi * 16 + lane15;
        boff[mi] = n * 64 + (quad ^ ((n >> 1) & 3)) * 16;
    }

    f4v acc[4][4];
#pragma unroll
    for (int mi = 0; mi < 4; ++mi)
#pragma unroll
        for (int ni = 0; ni < 4; ++ni)
            acc[mi][ni] = (f4v){0.f, 0.f, 0.f, 0.f};

    // prologue: stage k0 = 0 into buffer 0
    async_copy16(gA0, (char*)As[0] + ldsOff);
    async_copy16(gA1, (char*)As[0] + 4096 + ldsOff);
    async_copy16(gB0, (char*)Bs[0] + ldsOff);
    async_copy16(gB1, (char*)Bs[0] + 4096 + ldsOff);

    for (int k0 = 0; k0 < D_IN; k0 += BK) {
        int cur = (k0 >> 5) & 1;
        __syncthreads();                    // drains loads into buf[cur]
        if (k0 + BK < D_IN) {
            int nxt = cur ^ 1;
            async_copy16(gA0 + k0 + BK, (char*)As[nxt] + ldsOff);
            async_copy16(gA1 + k0 + BK, (char*)As[nxt] + 4096 + ldsOff);
            async_copy16(gB0 + k0 + BK, (char*)Bs[nxt] + ldsOff);
            async_copy16(gB1 + k0 + BK, (char*)Bs[nxt] + 4096 + ldsOff);
        }
        const char* ab = (const char*)As[cur];
        const char* bb = (const char*)Bs[cur];
        s8v a[4], b[4];
#pragma unroll
        for (int mi = 0; mi < 4; ++mi) a[mi] = *(const s8v*)(ab + aoff[mi]);
#pragma unroll
        for (int ni = 0; ni < 4; ++ni) b[ni] = *(const s8v*)(bb + boff[ni]);
#pragma unroll
        for (int mi = 0; mi < 4; ++mi)
#pragma unroll
            for (int ni = 0; ni < 4; ++ni)
                acc[mi][ni] = __builtin_amdgcn_mfma_f32_16x16x32_bf16(
                    a[mi], b[ni], acc[mi][ni], 0, 0, 0);
    }

    // epilogue: scale by gate weight, add bias, store bf16 to yslot
    int   ent[4][4];
    float wgt[4][4];
    bool  val[4][4];
#pragma unroll
    for (int mi = 0; mi < 4; ++mi)
#pragma unroll
        for (int r = 0; r < 4; ++r) {
            int grow = bm * BM + wm + mi * 16 + quad * 4 + r;
            bool v = grow < cnte;
            int en = v ? epe[grow] : 0;
            ent[mi][r] = en;
            wgt[mi][r] = v ? wslot[en] : 0.f;
            val[mi][r] = v;
        }
#pragma unroll
    for (int ni = 0; ni < 4; ++ni) {
        int col = bn * BN + wn + ni * 16 + lane15;
        float bev = be[e * D_OUT + col];
#pragma unroll
        for (int mi = 0; mi < 4; ++mi)
#pragma unroll
            for (int r = 0; r < 4; ++r)
                if (val[mi][r])
                    yslot[(size_t)ent[mi][r] * D_OUT + col] =
                        f2bf(wgt[mi][r] * (acc[mi][ni][r] + bev));
    }
}

// ------- combine (+ fused aux): y[t] = ys[2t] + ys[2t+1] --------------------
__global__ void combine_kernel(const ushort_t* __restrict__ yslot,
                               const float* __restrict__ psum,
                               const int* __restrict__ cnt,
                               float* __restrict__ out) {
    size_t i = ((size_t)blockIdx.x * 256 + threadIdx.x) * 4;
    size_t t = i >> 10;
    size_t h = i & 1023;
    const ushort_t* p0 = yslot + (2 * t) * D_OUT + h;
    ushort4 a = *(const ushort4*)p0;
    ushort4 b = *(const ushort4*)(p0 + D_OUT);
    float4 o;
    o.x = bf2f(a.x) + bf2f(b.x);
    o.y = bf2f(a.y) + bf2f(b.y);
    o.z = bf2f(a.z) + bf2f(b.z);
    o.w = bf2f(a.w) + bf2f(b.w);
    *(float4*)(out + i) = o;
    if (i == 0) {
        float s = 0.f;
#pragma unroll
        for (int e = 0; e < N_EXP; ++e)
            s += (psum[e] / (float)T_TOK) * ((float)cnt[e] / (float)(T_TOK * 2));
        out[(size_t)T_TOK * D_OUT] = (float)N_EXP * s;
    }
}

extern "C" void kernel_launch(void* const* d_in, const int* in_sizes, int n_in,
                              void* d_out, int out_size, void* d_ws, size_t ws_size,
                              hipStream_t stream) {
    const float* x  = (const float*)d_in[0];
    const float* Wr = (const float*)d_in[1];
    const float* br = (const float*)d_in[2];
    const float* We = (const float*)d_in[3];
    const float* be = (const float*)d_in[4];
    float* out = (float*)d_out;

    char* ws = (char*)d_ws;
    ushort_t* xb      = (ushort_t*)(ws);                    // 16 MiB
    ushort_t* Webt    = (ushort_t*)(ws + 16777216);         // 16 MiB
    ushort_t* yslot   = (ushort_t*)(ws + 33554432);         // 32 MiB (bf16)
    int*      entries = (int*)(ws + 67108864);              // 256 KiB
    float*    wslot   = (float*)(ws + 67371008);            // 64 KiB
    float*    psum    = (float*)(ws + 67436544);            // 32 B
    int*      cnt     = (int*)(ws + 67436576);              // 32 B

    hipLaunchKernelGGL(cast_transpose_we, dim3(16, 16, 8), dim3(256), 0, stream,
                       We, Webt, cnt, psum);
    hipLaunchKernelGGL(router_kernel, dim3(128), dim3(256), 0, stream,
                       x, Wr, br, xb, wslot, entries, cnt, psum);
    hipLaunchKernelGGL(moe_gemm, dim3(4096), dim3(256), 0, stream,
                       xb, Webt, be, entries, cnt, wslot, yslot);
    hipLaunchKernelGGL(combine_kernel, dim3(8192), dim3(256), 0, stream,
                       yslot, psum, cnt, out);
}